// Round 3
// baseline (304.066 us; speedup 1.0000x reference)
//
#include <hip/hip_runtime.h>
#include <cstdint>
#include <cstddef>

typedef __bf16 bf16;
typedef __bf16 bf16x4 __attribute__((ext_vector_type(4)));
typedef __bf16 bf16x8 __attribute__((ext_vector_type(8)));
typedef float f32x4 __attribute__((ext_vector_type(4)));
typedef float f32x16 __attribute__((ext_vector_type(16)));

typedef const __attribute__((address_space(1))) void* gas_ptr;
typedef __attribute__((address_space(3))) void* las_ptr;

#define GLOAD_LDS16(g, l) __builtin_amdgcn_global_load_lds((gas_ptr)(g), (las_ptr)(l), 16, 0, 0)

// ---------------- f32 -> bf16 convert (vectorized, grid-stride) ----------------
__global__ void cvt_f32_bf16(const float* __restrict__ in, bf16* __restrict__ out, int n4) {
  int i = blockIdx.x * blockDim.x + threadIdx.x;
  int stride = gridDim.x * blockDim.x;
  for (; i < n4; i += stride) {
    float4 v = reinterpret_cast<const float4*>(in)[i];
    bf16x4 o;
    o[0] = (bf16)v.x; o[1] = (bf16)v.y; o[2] = (bf16)v.z; o[3] = (bf16)v.w;
    reinterpret_cast<bf16x4*>(out)[i] = o;
  }
}

// ---------------- GEMM: C[M,N] = A[M,K] * B[N,K]^T  (both K-contiguous) --------
template <int MODE>
__global__ __launch_bounds__(256, 2) void gemm_bt(
    const bf16* __restrict__ A, const bf16* __restrict__ B,
    int M, int N, int K,
    bf16* __restrict__ qb, bf16* __restrict__ kb, bf16* __restrict__ vtb,
    float* __restrict__ out, const float* __restrict__ bias) {
  constexpr int BK = 32;
  __shared__ bf16 ldsA[128 * BK];
  __shared__ bf16 ldsB[128 * BK];
  const int tid = threadIdx.x;
  const int l = tid & 63;
  const int w = tid >> 6;
  const int wr = w >> 1, wc = w & 1;
  const int lr = l & 15, lg = l >> 4;
  const int brow = blockIdx.x * 128;
  const int bcol = blockIdx.y * 128;

  const int srow = tid >> 2;
  const int scol = (tid & 3) * 8;
  const bf16* Ag0 = A + (size_t)(brow + srow) * K + scol;
  const bf16* Ag1 = A + (size_t)(brow + 64 + srow) * K + scol;
  const bf16* Bg0 = B + (size_t)(bcol + srow) * K + scol;
  const bf16* Bg1 = B + (size_t)(bcol + 64 + srow) * K + scol;
  bf16* la0 = &ldsA[tid * 8];
  bf16* la1 = &ldsA[2048 + tid * 8];
  bf16* lb0 = &ldsB[tid * 8];
  bf16* lb1 = &ldsB[2048 + tid * 8];

  f32x4 acc[4][4] = {};

  for (int k0 = 0; k0 < K; k0 += BK) {
    GLOAD_LDS16(Ag0 + k0, la0);
    GLOAD_LDS16(Ag1 + k0, la1);
    GLOAD_LDS16(Bg0 + k0, lb0);
    GLOAD_LDS16(Bg1 + k0, lb1);
    __syncthreads();
    bf16x8 af[4], bfr[4];
#pragma unroll
    for (int mi = 0; mi < 4; mi++)
      af[mi] = *reinterpret_cast<const bf16x8*>(&ldsA[(wr * 64 + mi * 16 + lr) * BK + lg * 8]);
#pragma unroll
    for (int ni = 0; ni < 4; ni++)
      bfr[ni] = *reinterpret_cast<const bf16x8*>(&ldsB[(wc * 64 + ni * 16 + lr) * BK + lg * 8]);
#pragma unroll
    for (int mi = 0; mi < 4; mi++)
#pragma unroll
      for (int ni = 0; ni < 4; ni++)
        acc[mi][ni] = __builtin_amdgcn_mfma_f32_16x16x32_bf16(af[mi], bfr[ni], acc[mi][ni], 0, 0, 0);
    __syncthreads();
  }

#pragma unroll
  for (int mi = 0; mi < 4; mi++) {
#pragma unroll
    for (int r = 0; r < 4; r++) {
      const int m = brow + wr * 64 + mi * 16 + lg * 4 + r;
      const int bb = m >> 10;
      const int npos = m & 1023;
#pragma unroll
      for (int ni = 0; ni < 4; ni++) {
        const int e = bcol + wc * 64 + ni * 16 + lr;
        const float v = acc[mi][ni][r];
        if (MODE == 1) {
          out[(size_t)m * N + e] = v + bias[e];
        } else {
          if (e < 768) {
            const int h = e >> 6, d = e & 63;
            qb[(size_t)(bb * 12 + h) * 65536 + npos * 64 + d] = (bf16)v;
          } else if (e < 1536) {
            const int ee = e - 768;
            const int h = ee >> 6, d = ee & 63;
            kb[(size_t)(bb * 12 + h) * 65536 + npos * 64 + d] = (bf16)v;
          } else {
            const int ee = e - 1536;
            const int h = ee >> 6, d = ee & 63;
            vtb[(size_t)(bb * 12 + h) * 65536 + d * 1024 + npos] = (bf16)v;
          }
        }
      }
    }
  }
}

// ---------------- Flash attention, swapped-QK^T, 2-way split-K ----------------
// Q,K: [96][1024][64] bf16 ; Vt: [96][64][1024] bf16 ; Out bf16 [8][1024][768]
// grid (32 qtiles, 96 heads); block = 128 threads = 2 waves.
// Each block owns 32 q rows; wave w covers k in [w*512, w*512+512).
// Lane owns ONE q column (q0 + (lane&31)); end-of-kernel LDS merge of halves.
__global__ __launch_bounds__(128, 6) void attn_kernel(
    const bf16* __restrict__ Q, const bf16* __restrict__ K,
    const bf16* __restrict__ Vt, bf16* __restrict__ Out) {
  __shared__ float mstat[2][32];
  __shared__ float lstat[2][32];
  __shared__ float4 obuf[8][64];
  const int tid = threadIdx.x;
  const int l = tid & 63;
  const int w = tid >> 6;        // 0 or 1
  const int ql = l & 31;
  const int hi = l >> 5;
  const int bh = blockIdx.y;     // 0..95
  const int b = bh / 12, h = bh % 12;
  const int q0 = blockIdx.x * 32;
  const bf16* Qh = Q + (size_t)bh * 65536;
  const bf16* Kh = K + (size_t)bh * 65536;
  const bf16* Vh = Vt + (size_t)bh * 65536;

  // Q as B-operand of S^T = K.Q^T : col=q=lane&31, contraction d = s*16+hi*8+j
  bf16x8 qf[4];
#pragma unroll
  for (int s = 0; s < 4; s++)
    qf[s] = *reinterpret_cast<const bf16x8*>(&Qh[(size_t)(q0 + ql) * 64 + s * 16 + hi * 8]);

  f32x16 o[2] = {};
  float m = -1e30f, lsum = 0.f;

  const int kbeg = w * 512;
  for (int kt = kbeg; kt < kbeg + 512; kt += 64) {
    // ---- S^T tile: 2 x (32k x 32q) ----
    f32x16 st[2] = {};
#pragma unroll
    for (int kb = 0; kb < 2; kb++) {
#pragma unroll
      for (int s = 0; s < 4; s++) {
        bf16x8 kf = *reinterpret_cast<const bf16x8*>(
            &Kh[(size_t)(kt + kb * 32 + ql) * 64 + s * 16 + hi * 8]);
        st[kb] = __builtin_amdgcn_mfma_f32_32x32x16_bf16(kf, qf[s], st[kb], 0, 0, 0);
      }
    }
    // ---- issue V loads early ----
    bf16x8 vf[4][2];
#pragma unroll
    for (int t = 0; t < 4; t++)
#pragma unroll
      for (int dh = 0; dh < 2; dh++)
        vf[t][dh] = *reinterpret_cast<const bf16x8*>(
            &Vh[(size_t)(dh * 32 + ql) * 1024 + kt + t * 16 + hi * 8]);

    // ---- lane-local online softmax; tree reductions (depth ~5, not 32) ----
    float tmx[16];
#pragma unroll
    for (int r = 0; r < 16; r++) tmx[r] = fmaxf(st[0][r], st[1][r]);
#pragma unroll
    for (int d = 8; d >= 1; d >>= 1)
#pragma unroll
      for (int r = 0; r < d; r++) tmx[r] = fmaxf(tmx[r], tmx[r + d]);
    float tm = fmaxf(tmx[0], __shfl_xor(tmx[0], 32));
    const float mn = fmaxf(m, tm);
    const float a = __expf(m - mn);
    m = mn;
#pragma unroll
    for (int kb = 0; kb < 2; kb++)
#pragma unroll
      for (int r = 0; r < 16; r++) st[kb][r] = __expf(st[kb][r] - mn);
    float ts[16];
#pragma unroll
    for (int r = 0; r < 16; r++) ts[r] = st[0][r] + st[1][r];
#pragma unroll
    for (int d = 8; d >= 1; d >>= 1)
#pragma unroll
      for (int r = 0; r < d; r++) ts[r] += ts[r + d];
    const float rs = ts[0] + __shfl_xor(ts[0], 32);
    lsum = lsum * a + rs;
#pragma unroll
    for (int dh = 0; dh < 2; dh++)
#pragma unroll
      for (int r = 0; r < 16; r++) o[dh][r] *= a;

    // ---- P^T -> B-fragments via cvt_pk + permlane32_swap; O^T += V^T P^T ----
#pragma unroll
    for (int t = 0; t < 4; t++) {
      const int kb = t >> 1, c8 = (t & 1) * 8;
      uint32_t wA0, wA1, wB0, wB1;
      asm("v_cvt_pk_bf16_f32 %0, %1, %2" : "=v"(wA0) : "v"(st[kb][c8 + 0]), "v"(st[kb][c8 + 1]));
      asm("v_cvt_pk_bf16_f32 %0, %1, %2" : "=v"(wA1) : "v"(st[kb][c8 + 2]), "v"(st[kb][c8 + 3]));
      asm("v_cvt_pk_bf16_f32 %0, %1, %2" : "=v"(wB0) : "v"(st[kb][c8 + 4]), "v"(st[kb][c8 + 5]));
      asm("v_cvt_pk_bf16_f32 %0, %1, %2" : "=v"(wB1) : "v"(st[kb][c8 + 6]), "v"(st[kb][c8 + 7]));
      asm("v_permlane32_swap_b32 %0, %1" : "+v"(wA0), "+v"(wB0));
      asm("v_permlane32_swap_b32 %0, %1" : "+v"(wA1), "+v"(wB1));
      union { uint32_t u[4]; bf16x8 v; } pf;
      pf.u[0] = wA0; pf.u[1] = wA1; pf.u[2] = wB0; pf.u[3] = wB1;
#pragma unroll
      for (int dh = 0; dh < 2; dh++)
        o[dh] = __builtin_amdgcn_mfma_f32_32x32x16_bf16(vf[t][dh], pf.v, o[dh], 0, 0, 0);
    }
  }

  // ---- cross-wave merge: stats, then scaled-O exchange ----
  if (hi == 0) { mstat[w][ql] = m; lstat[w][ql] = lsum; }
  __syncthreads();
  const float m0 = mstat[0][ql], m1 = mstat[1][ql];
  const float M = fmaxf(m0, m1);
  const float L = lstat[0][ql] * __expf(m0 - M) + lstat[1][ql] * __expf(m1 - M);
  const float myscale = __expf(m - M);
#pragma unroll
  for (int dh = 0; dh < 2; dh++)
#pragma unroll
    for (int r = 0; r < 16; r++) o[dh][r] *= myscale;
  if (w == 1) {
#pragma unroll
    for (int dh = 0; dh < 2; dh++)
#pragma unroll
      for (int c = 0; c < 4; c++) {
        float4 t;
        t.x = o[dh][c * 4 + 0]; t.y = o[dh][c * 4 + 1];
        t.z = o[dh][c * 4 + 2]; t.w = o[dh][c * 4 + 3];
        obuf[dh * 4 + c][l] = t;
      }
  }
  __syncthreads();
  if (w == 0) {
    const float rl = 1.0f / L;
    bf16* orow = Out + (size_t)(b * 1024 + q0 + ql) * 768 + h * 64;
#pragma unroll
    for (int dh = 0; dh < 2; dh++)
#pragma unroll
      for (int rq = 0; rq < 4; rq++) {
        float4 t = obuf[dh * 4 + rq][l];
        union { ushort us[4]; uint2 v; } pk;
        const float v0 = (o[dh][rq * 4 + 0] + t.x) * rl;
        const float v1 = (o[dh][rq * 4 + 1] + t.y) * rl;
        const float v2 = (o[dh][rq * 4 + 2] + t.z) * rl;
        const float v3 = (o[dh][rq * 4 + 3] + t.w) * rl;
        pk.us[0] = __builtin_bit_cast(ushort, (bf16)v0);
        pk.us[1] = __builtin_bit_cast(ushort, (bf16)v1);
        pk.us[2] = __builtin_bit_cast(ushort, (bf16)v2);
        pk.us[3] = __builtin_bit_cast(ushort, (bf16)v3);
        *reinterpret_cast<uint2*>(&orow[dh * 32 + rq * 8 + hi * 4]) = pk.v;
      }
  }
}

// ---------------- launch ------------------------------------------------------
extern "C" void kernel_launch(void* const* d_in, const int* in_sizes, int n_in,
                              void* d_out, int out_size, void* d_ws, size_t ws_size,
                              hipStream_t stream) {
  const float* x = (const float*)d_in[0];
  const float* w_qkv = (const float*)d_in[1];
  const float* w_fc = (const float*)d_in[2];
  const float* b_fc = (const float*)d_in[3];
  float* out = (float*)d_out;
  char* ws = (char*)d_ws;

  bf16* xb = (bf16*)(ws);                    // 8192x768
  bf16* wqkb = (bf16*)(ws + 12582912);       // 2304x768
  bf16* wfcb = (bf16*)(ws + 16121856);       // 768x768
  bf16* qb = (bf16*)(ws + 17301504);         // 96x1024x64
  bf16* kb = (bf16*)(ws + 29884416);         // 96x1024x64
  bf16* vtb = (bf16*)(ws + 42467328);        // 96x64x1024
  bf16* aob = (bf16*)(ws + 55050240);        // 8192x768

  cvt_f32_bf16<<<2048, 256, 0, stream>>>(x, xb, 6291456 / 4);
  cvt_f32_bf16<<<1728, 256, 0, stream>>>(w_qkv, wqkb, 1769472 / 4);
  cvt_f32_bf16<<<576, 256, 0, stream>>>(w_fc, wfcb, 589824 / 4);

  gemm_bt<0><<<dim3(64, 18), 256, 0, stream>>>(xb, wqkb, 8192, 2304, 768,
                                               qb, kb, vtb, nullptr, nullptr);

  attn_kernel<<<dim3(32, 96), 128, 0, stream>>>(qb, kb, vtb, aob);

  gemm_bt<1><<<dim3(64, 6), 256, 0, stream>>>(aob, wfcb, 8192, 768, 768,
                                              nullptr, nullptr, nullptr, out, b_fc);
}

// Round 5
// 197.291 us; speedup vs baseline: 1.5412x; 1.5412x over previous
//
#include <hip/hip_runtime.h>
#include <cstdint>
#include <cstddef>

typedef __bf16 bf16;
typedef __bf16 bf16x4 __attribute__((ext_vector_type(4)));
typedef __bf16 bf16x8 __attribute__((ext_vector_type(8)));
typedef float f32x4 __attribute__((ext_vector_type(4)));
typedef float f32x16 __attribute__((ext_vector_type(16)));

typedef const __attribute__((address_space(1))) void* gas_ptr;
typedef __attribute__((address_space(3))) void* las_ptr;

#define GLOAD_LDS16(g, l) __builtin_amdgcn_global_load_lds((gas_ptr)(g), (las_ptr)(l), 16, 0, 0)

// ---------------- f32 -> bf16 convert (vectorized, grid-stride) ----------------
__global__ void cvt_f32_bf16(const float* __restrict__ in, bf16* __restrict__ out, int n4) {
  int i = blockIdx.x * blockDim.x + threadIdx.x;
  int stride = gridDim.x * blockDim.x;
  for (; i < n4; i += stride) {
    float4 v = reinterpret_cast<const float4*>(in)[i];
    bf16x4 o;
    o[0] = (bf16)v.x; o[1] = (bf16)v.y; o[2] = (bf16)v.z; o[3] = (bf16)v.w;
    reinterpret_cast<bf16x4*>(out)[i] = o;
  }
}

// ---------------- GEMM: C[M,N] = A[M,K] * B[N,K]^T  (both K-contiguous) --------
template <int MODE>
__global__ __launch_bounds__(256, 2) void gemm_bt(
    const bf16* __restrict__ A, const bf16* __restrict__ B,
    int M, int N, int K,
    bf16* __restrict__ qb, bf16* __restrict__ kb, bf16* __restrict__ vtb,
    float* __restrict__ out, const float* __restrict__ bias) {
  constexpr int BK = 32;
  __shared__ bf16 ldsA[128 * BK];
  __shared__ bf16 ldsB[128 * BK];
  const int tid = threadIdx.x;
  const int l = tid & 63;
  const int w = tid >> 6;
  const int wr = w >> 1, wc = w & 1;
  const int lr = l & 15, lg = l >> 4;
  const int brow = blockIdx.x * 128;
  const int bcol = blockIdx.y * 128;

  const int srow = tid >> 2;
  const int scol = (tid & 3) * 8;
  const bf16* Ag0 = A + (size_t)(brow + srow) * K + scol;
  const bf16* Ag1 = A + (size_t)(brow + 64 + srow) * K + scol;
  const bf16* Bg0 = B + (size_t)(bcol + srow) * K + scol;
  const bf16* Bg1 = B + (size_t)(bcol + 64 + srow) * K + scol;
  bf16* la0 = &ldsA[tid * 8];
  bf16* la1 = &ldsA[2048 + tid * 8];
  bf16* lb0 = &ldsB[tid * 8];
  bf16* lb1 = &ldsB[2048 + tid * 8];

  f32x4 acc[4][4] = {};

  for (int k0 = 0; k0 < K; k0 += BK) {
    GLOAD_LDS16(Ag0 + k0, la0);
    GLOAD_LDS16(Ag1 + k0, la1);
    GLOAD_LDS16(Bg0 + k0, lb0);
    GLOAD_LDS16(Bg1 + k0, lb1);
    __syncthreads();
    bf16x8 af[4], bfr[4];
#pragma unroll
    for (int mi = 0; mi < 4; mi++)
      af[mi] = *reinterpret_cast<const bf16x8*>(&ldsA[(wr * 64 + mi * 16 + lr) * BK + lg * 8]);
#pragma unroll
    for (int ni = 0; ni < 4; ni++)
      bfr[ni] = *reinterpret_cast<const bf16x8*>(&ldsB[(wc * 64 + ni * 16 + lr) * BK + lg * 8]);
#pragma unroll
    for (int mi = 0; mi < 4; mi++)
#pragma unroll
      for (int ni = 0; ni < 4; ni++)
        acc[mi][ni] = __builtin_amdgcn_mfma_f32_16x16x32_bf16(af[mi], bfr[ni], acc[mi][ni], 0, 0, 0);
    __syncthreads();
  }

#pragma unroll
  for (int mi = 0; mi < 4; mi++) {
#pragma unroll
    for (int r = 0; r < 4; r++) {
      const int m = brow + wr * 64 + mi * 16 + lg * 4 + r;
      const int bb = m >> 10;
      const int npos = m & 1023;
#pragma unroll
      for (int ni = 0; ni < 4; ni++) {
        const int e = bcol + wc * 64 + ni * 16 + lr;
        const float v = acc[mi][ni][r];
        if (MODE == 1) {
          out[(size_t)m * N + e] = v + bias[e];
        } else {
          if (e < 768) {
            const int h = e >> 6, d = e & 63;
            qb[(size_t)(bb * 12 + h) * 65536 + npos * 64 + d] = (bf16)v;
          } else if (e < 1536) {
            const int ee = e - 768;
            const int h = ee >> 6, d = ee & 63;
            kb[(size_t)(bb * 12 + h) * 65536 + npos * 64 + d] = (bf16)v;
          } else {
            const int ee = e - 1536;
            const int h = ee >> 6, d = ee & 63;
            vtb[(size_t)(bb * 12 + h) * 65536 + d * 1024 + npos] = (bf16)v;
          }
        }
      }
    }
  }
}

// ---------------- Flash attention, swapped-QK^T, 2-way split-K ----------------
// Q,K: [96][1024][64] bf16 ; Vt: [96][64][1024] bf16 ; Out bf16 [8][1024][768]
// grid (32 qtiles, 96 heads); block = 128 threads = 2 waves.
// Wave w covers k in [w*512, w*512+512); lane owns ONE q column (q0 + (l&31)).
// __launch_bounds__(128,4): VGPR budget 128 ~= live set; (128,6) spilled (r3).
__global__ __launch_bounds__(128, 4) void attn_kernel(
    const bf16* __restrict__ Q, const bf16* __restrict__ K,
    const bf16* __restrict__ Vt, bf16* __restrict__ Out) {
  __shared__ float mstat[2][32];
  __shared__ float lstat[2][32];
  __shared__ float4 obuf[8][64];
  const int tid = threadIdx.x;
  const int l = tid & 63;
  const int w = tid >> 6;        // 0 or 1
  const int ql = l & 31;
  const int hi = l >> 5;
  const int bh = blockIdx.y;     // 0..95
  const int b = bh / 12, h = bh % 12;
  const int q0 = blockIdx.x * 32;
  const bf16* Qh = Q + (size_t)bh * 65536;
  const bf16* Kh = K + (size_t)bh * 65536;
  const bf16* Vh = Vt + (size_t)bh * 65536;

  // Q as B-operand of S^T = K.Q^T : col=q=lane&31, contraction d = s*16+hi*8+j
  bf16x8 qf[4];
#pragma unroll
  for (int s = 0; s < 4; s++)
    qf[s] = *reinterpret_cast<const bf16x8*>(&Qh[(size_t)(q0 + ql) * 64 + s * 16 + hi * 8]);

  f32x16 o[2] = {};
  float m = -1e30f, lsum = 0.f;

  const int kbeg = w * 512;
  for (int kt = kbeg; kt < kbeg + 512; kt += 64) {
    // ---- S^T tile: 2 x (32k x 32q) ----
    f32x16 st[2] = {};
#pragma unroll
    for (int kb = 0; kb < 2; kb++) {
#pragma unroll
      for (int s = 0; s < 4; s++) {
        bf16x8 kf = *reinterpret_cast<const bf16x8*>(
            &Kh[(size_t)(kt + kb * 32 + ql) * 64 + s * 16 + hi * 8]);
        st[kb] = __builtin_amdgcn_mfma_f32_32x32x16_bf16(kf, qf[s], st[kb], 0, 0, 0);
      }
    }

    // ---- lane-local online softmax; tree reductions; T13 defer-max ----
    float tmx[16];
#pragma unroll
    for (int r = 0; r < 16; r++) tmx[r] = fmaxf(st[0][r], st[1][r]);
#pragma unroll
    for (int d = 8; d >= 1; d >>= 1)
#pragma unroll
      for (int r = 0; r < d; r++) tmx[r] = fmaxf(tmx[r], tmx[r + d]);
    float tm = fmaxf(tmx[0], __shfl_xor(tmx[0], 32));
    if (!__all(tm <= m + 8.0f)) {
      const float mn = fmaxf(m, tm);
      const float a = __expf(m - mn);
      m = mn;
      lsum *= a;
#pragma unroll
      for (int dh = 0; dh < 2; dh++)
#pragma unroll
        for (int r = 0; r < 16; r++) o[dh][r] *= a;
    }
#pragma unroll
    for (int kb = 0; kb < 2; kb++)
#pragma unroll
      for (int r = 0; r < 16; r++) st[kb][r] = __expf(st[kb][r] - m);
    float ts[16];
#pragma unroll
    for (int r = 0; r < 16; r++) ts[r] = st[0][r] + st[1][r];
#pragma unroll
    for (int d = 8; d >= 1; d >>= 1)
#pragma unroll
      for (int r = 0; r < d; r++) ts[r] += ts[r + d];
    lsum += ts[0] + __shfl_xor(ts[0], 32);

    // ---- P^T -> B-fragments via cvt_pk + permlane32_swap; O^T += V^T P^T ----
#pragma unroll
    for (int t = 0; t < 4; t++) {
      bf16x8 vf0 = *reinterpret_cast<const bf16x8*>(
          &Vh[(size_t)(0 * 32 + ql) * 1024 + kt + t * 16 + hi * 8]);
      bf16x8 vf1 = *reinterpret_cast<const bf16x8*>(
          &Vh[(size_t)(1 * 32 + ql) * 1024 + kt + t * 16 + hi * 8]);
      const int kb = t >> 1, c8 = (t & 1) * 8;
      uint32_t wA0, wA1, wB0, wB1;
      asm("v_cvt_pk_bf16_f32 %0, %1, %2" : "=v"(wA0) : "v"(st[kb][c8 + 0]), "v"(st[kb][c8 + 1]));
      asm("v_cvt_pk_bf16_f32 %0, %1, %2" : "=v"(wA1) : "v"(st[kb][c8 + 2]), "v"(st[kb][c8 + 3]));
      asm("v_cvt_pk_bf16_f32 %0, %1, %2" : "=v"(wB0) : "v"(st[kb][c8 + 4]), "v"(st[kb][c8 + 5]));
      asm("v_cvt_pk_bf16_f32 %0, %1, %2" : "=v"(wB1) : "v"(st[kb][c8 + 6]), "v"(st[kb][c8 + 7]));
      asm("v_permlane32_swap_b32 %0, %1" : "+v"(wA0), "+v"(wB0));
      asm("v_permlane32_swap_b32 %0, %1" : "+v"(wA1), "+v"(wB1));
      union { uint32_t u[4]; bf16x8 v; } pf;
      pf.u[0] = wA0; pf.u[1] = wA1; pf.u[2] = wB0; pf.u[3] = wB1;
      o[0] = __builtin_amdgcn_mfma_f32_32x32x16_bf16(vf0, pf.v, o[0], 0, 0, 0);
      o[1] = __builtin_amdgcn_mfma_f32_32x32x16_bf16(vf1, pf.v, o[1], 0, 0, 0);
    }
  }

  // ---- cross-wave merge: stats, then scaled-O exchange ----
  if (hi == 0) { mstat[w][ql] = m; lstat[w][ql] = lsum; }
  __syncthreads();
  const float m0 = mstat[0][ql], m1 = mstat[1][ql];
  const float M = fmaxf(m0, m1);
  const float L = lstat[0][ql] * __expf(m0 - M) + lstat[1][ql] * __expf(m1 - M);
  const float myscale = __expf(m - M);
#pragma unroll
  for (int dh = 0; dh < 2; dh++)
#pragma unroll
    for (int r = 0; r < 16; r++) o[dh][r] *= myscale;
  if (w == 1) {
#pragma unroll
    for (int dh = 0; dh < 2; dh++)
#pragma unroll
      for (int c = 0; c < 4; c++) {
        float4 t;
        t.x = o[dh][c * 4 + 0]; t.y = o[dh][c * 4 + 1];
        t.z = o[dh][c * 4 + 2]; t.w = o[dh][c * 4 + 3];
        obuf[dh * 4 + c][l] = t;
      }
  }
  __syncthreads();
  if (w == 0) {
    const float rl = 1.0f / L;
    bf16* orow = Out + (size_t)(b * 1024 + q0 + ql) * 768 + h * 64;
#pragma unroll
    for (int dh = 0; dh < 2; dh++)
#pragma unroll
      for (int rq = 0; rq < 4; rq++) {
        float4 t = obuf[dh * 4 + rq][l];
        union { ushort us[4]; uint2 v; } pk;
        const float v0 = (o[dh][rq * 4 + 0] + t.x) * rl;
        const float v1 = (o[dh][rq * 4 + 1] + t.y) * rl;
        const float v2 = (o[dh][rq * 4 + 2] + t.z) * rl;
        const float v3 = (o[dh][rq * 4 + 3] + t.w) * rl;
        pk.us[0] = __builtin_bit_cast(ushort, (bf16)v0);
        pk.us[1] = __builtin_bit_cast(ushort, (bf16)v1);
        pk.us[2] = __builtin_bit_cast(ushort, (bf16)v2);
        pk.us[3] = __builtin_bit_cast(ushort, (bf16)v3);
        *reinterpret_cast<uint2*>(&orow[dh * 32 + rq * 8 + hi * 4]) = pk.v;
      }
  }
}

// ---------------- launch ------------------------------------------------------
extern "C" void kernel_launch(void* const* d_in, const int* in_sizes, int n_in,
                              void* d_out, int out_size, void* d_ws, size_t ws_size,
                              hipStream_t stream) {
  const float* x = (const float*)d_in[0];
  const float* w_qkv = (const float*)d_in[1];
  const float* w_fc = (const float*)d_in[2];
  const float* b_fc = (const float*)d_in[3];
  float* out = (float*)d_out;
  char* ws = (char*)d_ws;

  bf16* xb = (bf16*)(ws);                    // 8192x768
  bf16* wqkb = (bf16*)(ws + 12582912);       // 2304x768
  bf16* wfcb = (bf16*)(ws + 16121856);       // 768x768
  bf16* qb = (bf16*)(ws + 17301504);         // 96x1024x64
  bf16* kb = (bf16*)(ws + 29884416);         // 96x1024x64
  bf16* vtb = (bf16*)(ws + 42467328);        // 96x64x1024
  bf16* aob = (bf16*)(ws + 55050240);        // 8192x768

  cvt_f32_bf16<<<2048, 256, 0, stream>>>(x, xb, 6291456 / 4);
  cvt_f32_bf16<<<1728, 256, 0, stream>>>(w_qkv, wqkb, 1769472 / 4);
  cvt_f32_bf16<<<576, 256, 0, stream>>>(w_fc, wfcb, 589824 / 4);

  gemm_bt<0><<<dim3(64, 18), 256, 0, stream>>>(xb, wqkb, 8192, 2304, 768,
                                               qb, kb, vtb, nullptr, nullptr);

  attn_kernel<<<dim3(32, 96), 128, 0, stream>>>(qb, kb, vtb, aob);

  gemm_bt<1><<<dim3(64, 6), 256, 0, stream>>>(aob, wfcb, 8192, 768, 768,
                                              nullptr, nullptr, nullptr, out, b_fc);
}

// Round 6
// 185.754 us; speedup vs baseline: 1.6369x; 1.0621x over previous
//
#include <hip/hip_runtime.h>
#include <cstdint>
#include <cstddef>

typedef __bf16 bf16;
typedef __bf16 bf16x4 __attribute__((ext_vector_type(4)));
typedef __bf16 bf16x8 __attribute__((ext_vector_type(8)));
typedef float f32x4 __attribute__((ext_vector_type(4)));
typedef float f32x16 __attribute__((ext_vector_type(16)));

typedef const __attribute__((address_space(1))) void* gas_ptr;
typedef __attribute__((address_space(3))) void* las_ptr;

#define GLOAD_LDS16(g, l) __builtin_amdgcn_global_load_lds((gas_ptr)(g), (las_ptr)(l), 16, 0, 0)

// ---------------- f32 -> bf16 convert (vectorized, grid-stride) ----------------
__global__ void cvt_f32_bf16(const float* __restrict__ in, bf16* __restrict__ out, int n4) {
  int i = blockIdx.x * blockDim.x + threadIdx.x;
  int stride = gridDim.x * blockDim.x;
  for (; i < n4; i += stride) {
    float4 v = reinterpret_cast<const float4*>(in)[i];
    bf16x4 o;
    o[0] = (bf16)v.x; o[1] = (bf16)v.y; o[2] = (bf16)v.z; o[3] = (bf16)v.w;
    reinterpret_cast<bf16x4*>(out)[i] = o;
  }
}

// ---------------- GEMM: C[M,N] = A[M,K] * B[N,K]^T  (both K-contiguous) --------
template <int MODE>
__global__ __launch_bounds__(256, 2) void gemm_bt(
    const bf16* __restrict__ A, const bf16* __restrict__ B,
    int M, int N, int K,
    bf16* __restrict__ qb, bf16* __restrict__ kb, bf16* __restrict__ vtb,
    float* __restrict__ out, const float* __restrict__ bias) {
  constexpr int BK = 32;
  __shared__ bf16 ldsA[128 * BK];
  __shared__ bf16 ldsB[128 * BK];
  const int tid = threadIdx.x;
  const int l = tid & 63;
  const int w = tid >> 6;
  const int wr = w >> 1, wc = w & 1;
  const int lr = l & 15, lg = l >> 4;
  const int brow = blockIdx.x * 128;
  const int bcol = blockIdx.y * 128;

  const int srow = tid >> 2;
  const int scol = (tid & 3) * 8;
  const bf16* Ag0 = A + (size_t)(brow + srow) * K + scol;
  const bf16* Ag1 = A + (size_t)(brow + 64 + srow) * K + scol;
  const bf16* Bg0 = B + (size_t)(bcol + srow) * K + scol;
  const bf16* Bg1 = B + (size_t)(bcol + 64 + srow) * K + scol;
  bf16* la0 = &ldsA[tid * 8];
  bf16* la1 = &ldsA[2048 + tid * 8];
  bf16* lb0 = &ldsB[tid * 8];
  bf16* lb1 = &ldsB[2048 + tid * 8];

  f32x4 acc[4][4] = {};

  for (int k0 = 0; k0 < K; k0 += BK) {
    GLOAD_LDS16(Ag0 + k0, la0);
    GLOAD_LDS16(Ag1 + k0, la1);
    GLOAD_LDS16(Bg0 + k0, lb0);
    GLOAD_LDS16(Bg1 + k0, lb1);
    __syncthreads();
    bf16x8 af[4], bfr[4];
#pragma unroll
    for (int mi = 0; mi < 4; mi++)
      af[mi] = *reinterpret_cast<const bf16x8*>(&ldsA[(wr * 64 + mi * 16 + lr) * BK + lg * 8]);
#pragma unroll
    for (int ni = 0; ni < 4; ni++)
      bfr[ni] = *reinterpret_cast<const bf16x8*>(&ldsB[(wc * 64 + ni * 16 + lr) * BK + lg * 8]);
#pragma unroll
    for (int mi = 0; mi < 4; mi++)
#pragma unroll
      for (int ni = 0; ni < 4; ni++)
        acc[mi][ni] = __builtin_amdgcn_mfma_f32_16x16x32_bf16(af[mi], bfr[ni], acc[mi][ni], 0, 0, 0);
    __syncthreads();
  }

#pragma unroll
  for (int mi = 0; mi < 4; mi++) {
#pragma unroll
    for (int r = 0; r < 4; r++) {
      const int m = brow + wr * 64 + mi * 16 + lg * 4 + r;
      const int bb = m >> 10;
      const int npos = m & 1023;
#pragma unroll
      for (int ni = 0; ni < 4; ni++) {
        const int e = bcol + wc * 64 + ni * 16 + lr;
        const float v = acc[mi][ni][r];
        if (MODE == 1) {
          out[(size_t)m * N + e] = v + bias[e];
        } else {
          if (e < 768) {
            const int h = e >> 6, d = e & 63;
            qb[(size_t)(bb * 12 + h) * 65536 + npos * 64 + d] = (bf16)v;
          } else if (e < 1536) {
            const int ee = e - 768;
            const int h = ee >> 6, d = ee & 63;
            kb[(size_t)(bb * 12 + h) * 65536 + npos * 64 + d] = (bf16)v;
          } else {
            const int ee = e - 1536;
            const int h = ee >> 6, d = ee & 63;
            vtb[(size_t)(bb * 12 + h) * 65536 + d * 1024 + npos] = (bf16)v;
          }
        }
      }
    }
  }
}

// ---------------- Flash attention, swapped-QK^T, K-prefetch pipeline ----------
// Q,K: [96][1024][64] bf16 ; Vt: [96][64][1024] bf16 ; Out bf16 [8][1024][768]
// grid (96 heads, 8 qtiles): linear wgid = h + 96*qt -> XCD = h%8, so each
// head's K/V is pinned to ONE XCD's L2 (12 heads x 256KB = 3MB < 4MB).
// Block 256 = 4 waves; wave w owns 32 q rows, sweeps all k (no merge).
// Pipeline: K for tile i+1 loaded into the SAME regs right after tile i's
// QK MFMAs consume them; V ping-pongs one t-step ahead; st converted to bf16
// P-fragments before PV so the f32 S tile dies early (VGPR peak ~150 < 168).
__global__ __launch_bounds__(256, 3) void attn_kernel(
    const bf16* __restrict__ Q, const bf16* __restrict__ K,
    const bf16* __restrict__ Vt, bf16* __restrict__ Out) {
  const int tid = threadIdx.x;
  const int l = tid & 63;
  const int w = tid >> 6;
  const int ql = l & 31;
  const int hi = l >> 5;
  const int bh = blockIdx.x;     // 0..95 (head-major -> XCD pinning)
  const int b = bh / 12, h = bh % 12;
  const int q0 = blockIdx.y * 128 + w * 32;
  const bf16* Qh = Q + (size_t)bh * 65536;
  const bf16* Kh = K + (size_t)bh * 65536;
  const bf16* Vh = Vt + (size_t)bh * 65536;

  // Q as B-operand of S^T = K.Q^T : col=q=lane&31, contraction d = s*16+hi*8+j
  bf16x8 qf[4];
#pragma unroll
  for (int s = 0; s < 4; s++)
    qf[s] = *reinterpret_cast<const bf16x8*>(&Qh[(size_t)(q0 + ql) * 64 + s * 16 + hi * 8]);

  f32x16 o[2] = {};
  float m = -1e30f, lsum = 0.f;

  // K fragments for the CURRENT tile (reloaded in-place for tile+1 after use)
  bf16x8 kf[2][4];
#pragma unroll
  for (int kb = 0; kb < 2; kb++)
#pragma unroll
    for (int s = 0; s < 4; s++)
      kf[kb][s] = *reinterpret_cast<const bf16x8*>(
          &Kh[(size_t)(kb * 32 + ql) * 64 + s * 16 + hi * 8]);

  for (int kt = 0; kt < 1024; kt += 64) {
    // ---- S^T tile: 2 x (32k x 32q); interleave the two acc chains ----
    f32x16 st[2] = {};
    __builtin_amdgcn_s_setprio(1);
#pragma unroll
    for (int s = 0; s < 4; s++) {
      st[0] = __builtin_amdgcn_mfma_f32_32x32x16_bf16(kf[0][s], qf[s], st[0], 0, 0, 0);
      st[1] = __builtin_amdgcn_mfma_f32_32x32x16_bf16(kf[1][s], qf[s], st[1], 0, 0, 0);
    }
    __builtin_amdgcn_s_setprio(0);

    // ---- prefetch NEXT tile's K into the same regs (now dead) ----
    {
      const int ktn = (kt + 64) & 1023;   // last iter wraps to 0 (harmless)
#pragma unroll
      for (int kb = 0; kb < 2; kb++)
#pragma unroll
        for (int s = 0; s < 4; s++)
          kf[kb][s] = *reinterpret_cast<const bf16x8*>(
              &Kh[(size_t)(ktn + kb * 32 + ql) * 64 + s * 16 + hi * 8]);
    }
    // ---- prefetch V for t=0,1 (ping-pong pair) ----
    bf16x8 vf[2][2];
#pragma unroll
    for (int t = 0; t < 2; t++)
#pragma unroll
      for (int dh = 0; dh < 2; dh++)
        vf[t][dh] = *reinterpret_cast<const bf16x8*>(
            &Vh[(size_t)(dh * 32 + ql) * 1024 + kt + t * 16 + hi * 8]);

    // ---- lane-local online softmax; tree reductions; T13 defer-max ----
    // (VALU here covers the K/V load latency issued above)
    float tmx[16];
#pragma unroll
    for (int r = 0; r < 16; r++) tmx[r] = fmaxf(st[0][r], st[1][r]);
#pragma unroll
    for (int d = 8; d >= 1; d >>= 1)
#pragma unroll
      for (int r = 0; r < d; r++) tmx[r] = fmaxf(tmx[r], tmx[r + d]);
    float tm = fmaxf(tmx[0], __shfl_xor(tmx[0], 32));
    if (!__all(tm <= m + 8.0f)) {
      const float mn = fmaxf(m, tm);
      const float a = __expf(m - mn);
      m = mn;
      lsum *= a;
#pragma unroll
      for (int dh = 0; dh < 2; dh++)
#pragma unroll
        for (int r = 0; r < 16; r++) o[dh][r] *= a;
    }
#pragma unroll
    for (int kb = 0; kb < 2; kb++)
#pragma unroll
      for (int r = 0; r < 16; r++) st[kb][r] = __expf(st[kb][r] - m);
    float ts[16];
#pragma unroll
    for (int r = 0; r < 16; r++) ts[r] = st[0][r] + st[1][r];
#pragma unroll
    for (int d = 8; d >= 1; d >>= 1)
#pragma unroll
      for (int r = 0; r < d; r++) ts[r] += ts[r + d];
    lsum += ts[0] + __shfl_xor(ts[0], 32);

    // ---- convert P^T to bf16 B-fragments for ALL t (frees st before PV) ----
    bf16x8 pfv[4];
#pragma unroll
    for (int t = 0; t < 4; t++) {
      const int kb = t >> 1, c8 = (t & 1) * 8;
      uint32_t wA0, wA1, wB0, wB1;
      asm("v_cvt_pk_bf16_f32 %0, %1, %2" : "=v"(wA0) : "v"(st[kb][c8 + 0]), "v"(st[kb][c8 + 1]));
      asm("v_cvt_pk_bf16_f32 %0, %1, %2" : "=v"(wA1) : "v"(st[kb][c8 + 2]), "v"(st[kb][c8 + 3]));
      asm("v_cvt_pk_bf16_f32 %0, %1, %2" : "=v"(wB0) : "v"(st[kb][c8 + 4]), "v"(st[kb][c8 + 5]));
      asm("v_cvt_pk_bf16_f32 %0, %1, %2" : "=v"(wB1) : "v"(st[kb][c8 + 6]), "v"(st[kb][c8 + 7]));
      asm("v_permlane32_swap_b32 %0, %1" : "+v"(wA0), "+v"(wB0));
      asm("v_permlane32_swap_b32 %0, %1" : "+v"(wA1), "+v"(wB1));
      union { uint32_t u[4]; bf16x8 v; } pf;
      pf.u[0] = wA0; pf.u[1] = wA1; pf.u[2] = wB0; pf.u[3] = wB1;
      pfv[t] = pf.v;
    }

    // ---- O^T += V^T P^T, V ping-pong one t ahead ----
#pragma unroll
    for (int t = 0; t < 4; t++) {
      if (t < 2) {
#pragma unroll
        for (int dh = 0; dh < 2; dh++)
          vf[t][dh] = vf[t][dh];  // current pair already resident
      }
      __builtin_amdgcn_s_setprio(1);
      o[0] = __builtin_amdgcn_mfma_f32_32x32x16_bf16(vf[t & 1][0], pfv[t], o[0], 0, 0, 0);
      o[1] = __builtin_amdgcn_mfma_f32_32x32x16_bf16(vf[t & 1][1], pfv[t], o[1], 0, 0, 0);
      __builtin_amdgcn_s_setprio(0);
      if (t < 2) {
        // prefetch V for t+2 into the slot just consumed
#pragma unroll
        for (int dh = 0; dh < 2; dh++)
          vf[t][dh] = *reinterpret_cast<const bf16x8*>(
              &Vh[(size_t)(dh * 32 + ql) * 1024 + kt + (t + 2) * 16 + hi * 8]);
      }
    }
  }

  // ---- normalize + store: Out[b, q0+ql, h*64 + d], 8B vector stores ----
  const float rl = 1.0f / lsum;
  bf16* orow = Out + (size_t)(b * 1024 + q0 + ql) * 768 + h * 64;
#pragma unroll
  for (int dh = 0; dh < 2; dh++)
#pragma unroll
    for (int rq = 0; rq < 4; rq++) {
      union { ushort us[4]; uint2 v; } pk;
#pragma unroll
      for (int i = 0; i < 4; i++) {
        const bf16 hv = (bf16)(o[dh][rq * 4 + i] * rl);
        pk.us[i] = __builtin_bit_cast(ushort, hv);
      }
      *reinterpret_cast<uint2*>(&orow[dh * 32 + rq * 8 + hi * 4]) = pk.v;
    }
}

// ---------------- launch ------------------------------------------------------
extern "C" void kernel_launch(void* const* d_in, const int* in_sizes, int n_in,
                              void* d_out, int out_size, void* d_ws, size_t ws_size,
                              hipStream_t stream) {
  const float* x = (const float*)d_in[0];
  const float* w_qkv = (const float*)d_in[1];
  const float* w_fc = (const float*)d_in[2];
  const float* b_fc = (const float*)d_in[3];
  float* out = (float*)d_out;
  char* ws = (char*)d_ws;

  bf16* xb = (bf16*)(ws);                    // 8192x768
  bf16* wqkb = (bf16*)(ws + 12582912);       // 2304x768
  bf16* wfcb = (bf16*)(ws + 16121856);       // 768x768
  bf16* qb = (bf16*)(ws + 17301504);         // 96x1024x64
  bf16* kb = (bf16*)(ws + 29884416);         // 96x1024x64
  bf16* vtb = (bf16*)(ws + 42467328);        // 96x64x1024
  bf16* aob = (bf16*)(ws + 55050240);        // 8192x768

  cvt_f32_bf16<<<2048, 256, 0, stream>>>(x, xb, 6291456 / 4);
  cvt_f32_bf16<<<1728, 256, 0, stream>>>(w_qkv, wqkb, 1769472 / 4);
  cvt_f32_bf16<<<576, 256, 0, stream>>>(w_fc, wfcb, 589824 / 4);

  gemm_bt<0><<<dim3(64, 18), 256, 0, stream>>>(xb, wqkb, 8192, 2304, 768,
                                               qb, kb, vtb, nullptr, nullptr);

  attn_kernel<<<dim3(96, 8), 256, 0, stream>>>(qb, kb, vtb, aob);

  gemm_bt<1><<<dim3(64, 6), 256, 0, stream>>>(aob, wfcb, 8192, 768, 768,
                                              nullptr, nullptr, nullptr, out, b_fc);
}